// Round 2
// baseline (983.503 us; speedup 1.0000x reference)
//
#include <hip/hip_runtime.h>
#include <hip/hip_bf16.h>
#include <math.h>

typedef __bf16 bf16x8 __attribute__((ext_vector_type(8)));
typedef float f32x4 __attribute__((ext_vector_type(4)));
typedef unsigned int u32x4 __attribute__((ext_vector_type(4)));

#define SEQ 1500
#define CDIM 1280
#define NHEAD 20
#define DHEAD 64
#define NMLP 5120

// ---------------- dtype detection: bf16 (flag=1) vs fp32 (flag=0) ----------
// For bf16 input pairs, the low 16 bits of each u32 word are a genuine bf16
// ~N(0,1) value -> exponent field in [~110,130]. For fp32 input, the low 16
// bits are random mantissa bits -> exponent field uniform over [0,255].
__global__ void detect_kernel(const unsigned int* __restrict__ xw,
                              int* __restrict__ flag) {
  __shared__ int cnt[256];
  const unsigned int w = xw[threadIdx.x];
  const unsigned int e = (w >> 7) & 0xFF;
  cnt[threadIdx.x] = (e >= 100 && e <= 150) ? 1 : 0;
  __syncthreads();
  for (int s = 128; s > 0; s >>= 1) {
    if (threadIdx.x < (unsigned)s) cnt[threadIdx.x] += cnt[threadIdx.x + s];
    __syncthreads();
  }
  if (threadIdx.x == 0) flag[0] = (cnt[0] >= 160) ? 1 : 0;
}

// ---------------- elementwise convert to bf16 (dtype-adaptive) -------------
__global__ __launch_bounds__(256) void convert_kernel(const void* __restrict__ src,
                                                      __bf16* __restrict__ dst,
                                                      int n, const int* __restrict__ flag) {
  const int isbf = flag[0];
  int i = blockIdx.x * 256 + threadIdx.x;
  const int stride = gridDim.x * 256;
  if (isbf) {
    const __bf16* s = (const __bf16*)src;
    for (; i < n; i += stride) dst[i] = s[i];
  } else {
    const float* s = (const float*)src;
    for (; i < n; i += stride) dst[i] = (__bf16)s[i];
  }
}

// ---------------- weight transpose: in (K,N) -> out (N,K), bf16 out --------
__global__ __launch_bounds__(256) void transpose_kernel(const void* __restrict__ in,
                                                        __bf16* __restrict__ out,
                                                        int K, int N,
                                                        const int* __restrict__ flag) {
  __shared__ __bf16 t[32][33];
  const int isbf = flag[0];
  const int tx = threadIdx.x, ty = threadIdx.y;
  const int n0 = blockIdx.x * 32, k0 = blockIdx.y * 32;
  if (isbf) {
    const __bf16* s = (const __bf16*)in;
#pragma unroll
    for (int i = ty; i < 32; i += 8)
      t[i][tx] = s[(size_t)(k0 + i) * N + n0 + tx];
  } else {
    const float* s = (const float*)in;
#pragma unroll
    for (int i = ty; i < 32; i += 8)
      t[i][tx] = (__bf16)s[(size_t)(k0 + i) * N + n0 + tx];
  }
  __syncthreads();
#pragma unroll
  for (int i = ty; i < 32; i += 8)
    out[(size_t)(n0 + i) * K + k0 + tx] = t[tx][i];
}

// ---------------- layernorm: 1 block per row, 1280 = 5*256 ----------------
__global__ __launch_bounds__(256) void ln_kernel(const __bf16* __restrict__ X,
                                                 const __bf16* __restrict__ gamma,
                                                 const __bf16* __restrict__ beta,
                                                 __bf16* __restrict__ Y) {
  const int row = blockIdx.x;
  const __bf16* xr = X + (size_t)row * CDIM;
  float v[5];
  float s = 0.f, s2 = 0.f;
#pragma unroll
  for (int i = 0; i < 5; ++i) {
    v[i] = (float)xr[threadIdx.x + 256 * i];
    s += v[i];
    s2 += v[i] * v[i];
  }
  const int lane = threadIdx.x & 63, wv = threadIdx.x >> 6;
#pragma unroll
  for (int off = 32; off > 0; off >>= 1) {
    s += __shfl_down(s, off);
    s2 += __shfl_down(s2, off);
  }
  __shared__ float red[8];
  if (lane == 0) { red[wv] = s; red[4 + wv] = s2; }
  __syncthreads();
  s = red[0] + red[1] + red[2] + red[3];
  s2 = red[4] + red[5] + red[6] + red[7];
  const float mu = s * (1.f / CDIM);
  const float var = s2 * (1.f / CDIM) - mu * mu;
  const float rstd = rsqrtf(fmaxf(var, 0.f) + 1e-5f);
#pragma unroll
  for (int i = 0; i < 5; ++i) {
    const int c = threadIdx.x + 256 * i;
    Y[(size_t)row * CDIM + c] =
        (__bf16)((v[i] - mu) * rstd * (float)gamma[c] + (float)beta[c]);
  }
}

// ---------------- GEMM: C[M,N] = A[M,K] @ Bt[N,K]^T (+bias, gelu, resid) ----
// 128x128 tile, BK=32, 4 waves of 64x64, 16x16x32 bf16 MFMA.
__device__ __forceinline__ void gemm_tile(const __bf16* __restrict__ A,
                                          const __bf16* __restrict__ Bt,
                                          const __bf16* __restrict__ bias,
                                          const __bf16* __restrict__ resid,
                                          void* __restrict__ Cv,
                                          int M, int N, int K, int bm, int bn,
                                          bool gelu, int finalOut,
                                          const int* __restrict__ flag) {
  __shared__ __bf16 As[128 * 40];  // [m][k], stride 40 (80B, 16B-aligned rows)
  __shared__ __bf16 Bs[128 * 40];  // [n][k]
  const int tid = threadIdx.x;
  const int lane = tid & 63, wave = tid >> 6;
  const int wm = (wave >> 1) * 64, wn = (wave & 1) * 64;
  const int l16 = lane & 15, kq = (lane >> 4) << 3;
  const int r0 = tid >> 2;         // 0..63
  const int kc = (tid & 3) << 3;   // 0,8,16,24
  const int outbf = finalOut ? flag[0] : 1;

  f32x4 acc[4][4];
  const f32x4 zero = {0.f, 0.f, 0.f, 0.f};
#pragma unroll
  for (int i = 0; i < 4; ++i)
#pragma unroll
    for (int j = 0; j < 4; ++j) acc[i][j] = zero;

  for (int k0 = 0; k0 < K; k0 += 32) {
#pragma unroll
    for (int it = 0; it < 2; ++it) {
      const int row = r0 + it * 64;
      int ga = bm * 128 + row;
      if (ga > M - 1) ga = M - 1;  // clamp: garbage rows never stored
      *(u32x4*)(&As[row * 40 + kc]) = *(const u32x4*)(A + (size_t)ga * K + k0 + kc);
      const int gb = bn * 128 + row;  // N is always a multiple of 128
      *(u32x4*)(&Bs[row * 40 + kc]) = *(const u32x4*)(Bt + (size_t)gb * K + k0 + kc);
    }
    __syncthreads();
    bf16x8 af[4], bfr[4];
#pragma unroll
    for (int i = 0; i < 4; ++i)
      af[i] = *(const bf16x8*)(&As[(wm + i * 16 + l16) * 40 + kq]);
#pragma unroll
    for (int j = 0; j < 4; ++j)
      bfr[j] = *(const bf16x8*)(&Bs[(wn + j * 16 + l16) * 40 + kq]);
#pragma unroll
    for (int i = 0; i < 4; ++i)
#pragma unroll
      for (int j = 0; j < 4; ++j)
        acc[i][j] = __builtin_amdgcn_mfma_f32_16x16x32_bf16(af[i], bfr[j],
                                                            acc[i][j], 0, 0, 0);
    __syncthreads();
  }

  // epilogue: D[row][col], col = lane&15, row = (lane>>4)*4 + r  (m89-verified)
  const int rq4 = (lane >> 4) * 4;
#pragma unroll
  for (int i = 0; i < 4; ++i) {
#pragma unroll
    for (int r = 0; r < 4; ++r) {
      const int grow = bm * 128 + wm + i * 16 + rq4 + r;
      if (grow >= M) continue;
#pragma unroll
      for (int j = 0; j < 4; ++j) {
        const int gcol = bn * 128 + wn + j * 16 + l16;
        float vv = acc[i][j][r];
        if (bias) vv += (float)bias[gcol];
        if (gelu) vv = 0.5f * vv * (1.f + erff(vv * 0.70710678118654752f));
        if (resid) vv += (float)resid[(size_t)grow * N + gcol];
        if (outbf) ((__bf16*)Cv)[(size_t)grow * N + gcol] = (__bf16)vv;
        else       ((float*)Cv)[(size_t)grow * N + gcol] = vv;
      }
    }
  }
}

__global__ __launch_bounds__(256) void gemm_kernel(const __bf16* __restrict__ A,
                                                   const __bf16* __restrict__ Bt,
                                                   const __bf16* __restrict__ bias,
                                                   const __bf16* __restrict__ resid,
                                                   void* __restrict__ C,
                                                   int M, int N, int K, int gelu,
                                                   int finalOut,
                                                   const int* __restrict__ flag) {
  gemm_tile(A, Bt, bias, resid, C, M, N, K, blockIdx.x, blockIdx.y, gelu != 0,
            finalOut, flag);
}

// fused Q/K/V: grid.y = 30 -> (which, bn)
__global__ __launch_bounds__(256) void gemm_qkv_kernel(const __bf16* __restrict__ A,
                                                       const __bf16* __restrict__ Wqt,
                                                       const __bf16* __restrict__ Wkt,
                                                       const __bf16* __restrict__ Wvt,
                                                       const __bf16* __restrict__ bq,
                                                       const __bf16* __restrict__ bv,
                                                       __bf16* __restrict__ Q,
                                                       __bf16* __restrict__ Ko,
                                                       __bf16* __restrict__ V,
                                                       const int* __restrict__ flag) {
  const int which = blockIdx.y / 10, bn = blockIdx.y % 10;
  const __bf16* Bt = (which == 0) ? Wqt : ((which == 1) ? Wkt : Wvt);
  const __bf16* bias = (which == 0) ? bq : ((which == 1) ? (const __bf16*)nullptr : bv);
  __bf16* C = (which == 0) ? Q : ((which == 1) ? Ko : V);
  gemm_tile(A, Bt, bias, nullptr, C, SEQ, CDIM, CDIM, blockIdx.x, bn, false, 0, flag);
}

// ---------------- attention: block = (16 queries) x (1 head) ----------------
__global__ __launch_bounds__(256) void attn_kernel(const __bf16* __restrict__ Q,
                                                   const __bf16* __restrict__ Kk,
                                                   const __bf16* __restrict__ V,
                                                   __bf16* __restrict__ O) {
  const int h = blockIdx.y;
  const int q0 = blockIdx.x * 16;
  const int tid = threadIdx.x;

  __shared__ float qs[16][68];
  __shared__ float kvs[64][68];
  __shared__ __bf16 sc[16][1544];
  __shared__ float ssum[16];

#pragma unroll
  for (int e = 0; e < 4; ++e) {
    const int i = tid + 256 * e;
    const int r = i >> 6, d = i & 63;
    const int gr = q0 + r;
    float val = 0.f;
    if (gr < SEQ) val = 0.125f * (float)Q[(size_t)gr * CDIM + h * DHEAD + d];
    qs[r][d] = val;
  }
  __syncthreads();

  const int qrow = tid & 15;
  const int kb16 = tid >> 4;
  const int skey = tid >> 2;
  const int sdg = (tid & 3) << 4;

  // ---- Phase A: scores ----
  for (int kt = 0; kt < 24; ++kt) {
    const int key0 = kt * 64;
    {
      const int gk = key0 + skey;
      bf16x8 a = {}, b = {};
      if (gk < SEQ) {
        const __bf16* src = Kk + (size_t)gk * CDIM + h * DHEAD + sdg;
        a = *(const bf16x8*)(src);
        b = *(const bf16x8*)(src + 8);
      }
#pragma unroll
      for (int e = 0; e < 8; ++e) {
        kvs[skey][sdg + e] = (float)a[e];
        kvs[skey][sdg + 8 + e] = (float)b[e];
      }
    }
    __syncthreads();
    float accp[4] = {0.f, 0.f, 0.f, 0.f};
#pragma unroll 4
    for (int d = 0; d < 64; ++d) {
      const float qv = qs[qrow][d];
#pragma unroll
      for (int p = 0; p < 4; ++p) accp[p] += qv * kvs[kb16 + 16 * p][d];
    }
#pragma unroll
    for (int p = 0; p < 4; ++p) {
      const int kk = kb16 + 16 * p;
      sc[qrow][key0 + kk] = (key0 + kk < SEQ) ? (__bf16)accp[p] : (__bf16)(-30000.f);
    }
    __syncthreads();
  }

  // ---- Phase B: softmax (per-wave rows) ----
  const int wv = tid >> 6, lane = tid & 63;
#pragma unroll
  for (int rr = 0; rr < 4; ++rr) {
    const int row = wv * 4 + rr;
    float mx = -30000.f;
    for (int c = lane; c < 1536; c += 64) mx = fmaxf(mx, (float)sc[row][c]);
#pragma unroll
    for (int off = 32; off > 0; off >>= 1) mx = fmaxf(mx, __shfl_xor(mx, off));
    float sum = 0.f;
    for (int c = lane; c < 1536; c += 64) {
      const float e = __expf((float)sc[row][c] - mx);
      sum += e;
      sc[row][c] = (__bf16)e;
    }
#pragma unroll
    for (int off = 32; off > 0; off >>= 1) sum += __shfl_xor(sum, off);
    if (lane == 0) ssum[row] = sum;
  }

  // ---- Phase C: O = P @ V ----
  const int d0 = (tid >> 4) << 2;
  float oacc[4] = {0.f, 0.f, 0.f, 0.f};
  for (int kt = 0; kt < 24; ++kt) {
    __syncthreads();
    {
      const int gk = kt * 64 + skey;
      bf16x8 a = {}, b = {};
      if (gk < SEQ) {
        const __bf16* src = V + (size_t)gk * CDIM + h * DHEAD + sdg;
        a = *(const bf16x8*)(src);
        b = *(const bf16x8*)(src + 8);
      }
#pragma unroll
      for (int e = 0; e < 8; ++e) {
        kvs[skey][sdg + e] = (float)a[e];
        kvs[skey][sdg + 8 + e] = (float)b[e];
      }
    }
    __syncthreads();
    const int key0 = kt * 64;
#pragma unroll 4
    for (int kk = 0; kk < 64; ++kk) {
      const float p = (float)sc[qrow][key0 + kk];
#pragma unroll
      for (int dd = 0; dd < 4; ++dd) oacc[dd] += p * kvs[kk][d0 + dd];
    }
  }
  const int gr = q0 + qrow;
  if (gr < SEQ) {
    const float inv = 1.f / ssum[qrow];
#pragma unroll
    for (int dd = 0; dd < 4; ++dd)
      O[(size_t)gr * CDIM + h * DHEAD + d0 + dd] = (__bf16)(oacc[dd] * inv);
  }
}

// ---------------- launch ----------------
extern "C" void kernel_launch(void* const* d_in, const int* in_sizes, int n_in,
                              void* d_out, int out_size, void* d_ws, size_t ws_size,
                              hipStream_t stream) {
  const void* x   = d_in[0];
  const void* Wq  = d_in[1];
  const void* bq  = d_in[2];
  const void* Wk  = d_in[3];
  const void* Wv  = d_in[4];
  const void* bv  = d_in[5];
  const void* Wo  = d_in[6];
  const void* bo  = d_in[7];
  const void* g1  = d_in[8];
  const void* be1 = d_in[9];
  const void* g2  = d_in[10];
  const void* be2 = d_in[11];
  const void* W1  = d_in[12];
  const void* bm1 = d_in[13];
  const void* W2  = d_in[14];
  const void* bm2 = d_in[15];

  char* ws = (char*)d_ws;
  size_t off = 0;
  auto alloc = [&](size_t elems) {
    __bf16* p = (__bf16*)(ws + off);
    off += elems * sizeof(__bf16);
    return p;
  };
  __bf16* Wqt = alloc((size_t)CDIM * CDIM);
  __bf16* Wkt = alloc((size_t)CDIM * CDIM);
  __bf16* Wvt = alloc((size_t)CDIM * CDIM);
  __bf16* Wot = alloc((size_t)CDIM * CDIM);
  __bf16* W1t = alloc((size_t)CDIM * NMLP);
  __bf16* W2t = alloc((size_t)CDIM * NMLP);
  __bf16* hb  = alloc((size_t)SEQ * CDIM);   // h / later attn-out
  __bf16* qb  = alloc((size_t)SEQ * CDIM);   // q / later x1
  __bf16* kb  = alloc((size_t)SEQ * CDIM);   // k / later h2
  __bf16* vb  = alloc((size_t)SEQ * CDIM);   // v
  __bf16* mb  = alloc((size_t)SEQ * NMLP);   // mlp hidden
  __bf16* xb  = alloc((size_t)SEQ * CDIM);   // x converted to bf16
  __bf16* pb  = alloc(16384);                // packed small params
  int* flag = (int*)(ws + off);

  __bf16* bq_b  = pb + 0;
  __bf16* bv_b  = pb + 1280;
  __bf16* bo_b  = pb + 2560;
  __bf16* g1_b  = pb + 3840;
  __bf16* be1_b = pb + 5120;
  __bf16* g2_b  = pb + 6400;
  __bf16* be2_b = pb + 7680;
  __bf16* b1_b  = pb + 8960;   // 5120
  __bf16* b2_b  = pb + 14080;

  detect_kernel<<<1, 256, 0, stream>>>((const unsigned int*)x, flag);

  convert_kernel<<<960, 256, 0, stream>>>(x, xb, SEQ * CDIM, flag);
  convert_kernel<<<5, 256, 0, stream>>>(bq, bq_b, CDIM, flag);
  convert_kernel<<<5, 256, 0, stream>>>(bv, bv_b, CDIM, flag);
  convert_kernel<<<5, 256, 0, stream>>>(bo, bo_b, CDIM, flag);
  convert_kernel<<<5, 256, 0, stream>>>(g1, g1_b, CDIM, flag);
  convert_kernel<<<5, 256, 0, stream>>>(be1, be1_b, CDIM, flag);
  convert_kernel<<<5, 256, 0, stream>>>(g2, g2_b, CDIM, flag);
  convert_kernel<<<5, 256, 0, stream>>>(be2, be2_b, CDIM, flag);
  convert_kernel<<<20, 256, 0, stream>>>(bm1, b1_b, NMLP, flag);
  convert_kernel<<<5, 256, 0, stream>>>(bm2, b2_b, CDIM, flag);

  const dim3 tb(32, 8);
  transpose_kernel<<<dim3(40, 40), tb, 0, stream>>>(Wq, Wqt, CDIM, CDIM, flag);
  transpose_kernel<<<dim3(40, 40), tb, 0, stream>>>(Wk, Wkt, CDIM, CDIM, flag);
  transpose_kernel<<<dim3(40, 40), tb, 0, stream>>>(Wv, Wvt, CDIM, CDIM, flag);
  transpose_kernel<<<dim3(40, 40), tb, 0, stream>>>(Wo, Wot, CDIM, CDIM, flag);
  transpose_kernel<<<dim3(160, 40), tb, 0, stream>>>(W1, W1t, CDIM, NMLP, flag);
  transpose_kernel<<<dim3(40, 160), tb, 0, stream>>>(W2, W2t, NMLP, CDIM, flag);

  ln_kernel<<<SEQ, 256, 0, stream>>>(xb, g1_b, be1_b, hb);
  gemm_qkv_kernel<<<dim3(12, 30), 256, 0, stream>>>(hb, Wqt, Wkt, Wvt, bq_b, bv_b,
                                                    qb, kb, vb, flag);
  attn_kernel<<<dim3(94, NHEAD), 256, 0, stream>>>(qb, kb, vb, hb);
  // x1 = x + attn @ Wo + bo   -> qb
  gemm_kernel<<<dim3(12, 10), 256, 0, stream>>>(hb, Wot, bo_b, xb, qb,
                                                SEQ, CDIM, CDIM, 0, 0, flag);
  // h2 = LN2(x1) -> kb
  ln_kernel<<<SEQ, 256, 0, stream>>>(qb, g2_b, be2_b, kb);
  // m = gelu(h2 @ W1 + b1)
  gemm_kernel<<<dim3(12, 40), 256, 0, stream>>>(kb, W1t, b1_b, nullptr, mb,
                                                SEQ, NMLP, CDIM, 1, 0, flag);
  // out = x1 + m @ W2 + b2  (output dtype per flag)
  gemm_kernel<<<dim3(12, 10), 256, 0, stream>>>(mb, W2t, b2_b, qb, d_out,
                                                SEQ, CDIM, NMLP, 0, 1, flag);
}

// Round 3
// 569.282 us; speedup vs baseline: 1.7276x; 1.7276x over previous
//
#include <hip/hip_runtime.h>
#include <hip/hip_bf16.h>
#include <math.h>

typedef __bf16 bf16x8 __attribute__((ext_vector_type(8)));
typedef float f32x4 __attribute__((ext_vector_type(4)));
typedef unsigned int u32x4 __attribute__((ext_vector_type(4)));

#define SEQ 1500
#define CDIM 1280
#define NHEAD 20
#define DHEAD 64
#define NMLP 5120
#define VTLD 1504   // leading dim of transposed V (47*32)
#define APAD 72     // attention LDS stride (144B: bank-spread)

#define GLOAD_LDS16(gp, lp)                                                    \
  __builtin_amdgcn_global_load_lds(                                            \
      (const __attribute__((address_space(1))) unsigned int*)(gp),             \
      (__attribute__((address_space(3))) unsigned int*)(lp), 16, 0, 0)

// ---------------- dtype detection: bf16 (flag=1) vs fp32 (flag=0) ----------
__global__ void detect_kernel(const unsigned int* __restrict__ xw,
                              int* __restrict__ flag) {
  __shared__ int cnt[256];
  const unsigned int w = xw[threadIdx.x];
  const unsigned int e = (w >> 7) & 0xFF;
  cnt[threadIdx.x] = (e >= 100 && e <= 150) ? 1 : 0;
  __syncthreads();
  for (int s = 128; s > 0; s >>= 1) {
    if (threadIdx.x < (unsigned)s) cnt[threadIdx.x] += cnt[threadIdx.x + s];
    __syncthreads();
  }
  if (threadIdx.x == 0) flag[0] = (cnt[0] >= 160) ? 1 : 0;
}

// ---------------- elementwise convert to bf16 (dtype-adaptive) -------------
__global__ __launch_bounds__(256) void convert_kernel(const void* __restrict__ src,
                                                      __bf16* __restrict__ dst,
                                                      int n, const int* __restrict__ flag) {
  const int isbf = flag[0];
  int i = blockIdx.x * 256 + threadIdx.x;
  const int stride = gridDim.x * 256;
  if (isbf) {
    const __bf16* s = (const __bf16*)src;
    for (; i < n; i += stride) dst[i] = s[i];
  } else {
    const float* s = (const float*)src;
    for (; i < n; i += stride) dst[i] = (__bf16)s[i];
  }
}

// ---------------- weight transpose: in (K,N) -> out (N,K), bf16 out --------
__global__ __launch_bounds__(256) void transpose_kernel(const void* __restrict__ in,
                                                        __bf16* __restrict__ out,
                                                        int K, int N,
                                                        const int* __restrict__ flag) {
  __shared__ __bf16 t[32][33];
  const int isbf = flag[0];
  const int tx = threadIdx.x, ty = threadIdx.y;
  const int n0 = blockIdx.x * 32, k0 = blockIdx.y * 32;
  if (isbf) {
    const __bf16* s = (const __bf16*)in;
#pragma unroll
    for (int i = ty; i < 32; i += 8)
      t[i][tx] = s[(size_t)(k0 + i) * N + n0 + tx];
  } else {
    const float* s = (const float*)in;
#pragma unroll
    for (int i = ty; i < 32; i += 8)
      t[i][tx] = (__bf16)s[(size_t)(k0 + i) * N + n0 + tx];
  }
  __syncthreads();
#pragma unroll
  for (int i = ty; i < 32; i += 8)
    out[(size_t)(n0 + i) * K + k0 + tx] = t[tx][i];
}

// ---------------- activation transpose: [K=1500][N] -> [N][VTLD] -----------
__global__ __launch_bounds__(256) void transpose_act_kernel(const __bf16* __restrict__ in,
                                                            __bf16* __restrict__ out) {
  __shared__ __bf16 t[32][33];
  const int tx = threadIdx.x, ty = threadIdx.y;
  const int n0 = blockIdx.x * 32, k0 = blockIdx.y * 32;
#pragma unroll
  for (int i = ty; i < 32; i += 8) {
    const int k = k0 + i;
    t[i][tx] = (k < SEQ) ? in[(size_t)k * CDIM + n0 + tx] : (__bf16)0.f;
  }
  __syncthreads();
#pragma unroll
  for (int i = ty; i < 32; i += 8) {
    const int kk = k0 + tx;
    if (kk < VTLD) out[(size_t)(n0 + i) * VTLD + kk] = t[tx][i];
  }
}

// ---------------- layernorm: 1 block per row, 1280 = 5*256 ----------------
__global__ __launch_bounds__(256) void ln_kernel(const __bf16* __restrict__ X,
                                                 const __bf16* __restrict__ gamma,
                                                 const __bf16* __restrict__ beta,
                                                 __bf16* __restrict__ Y) {
  const int row = blockIdx.x;
  const __bf16* xr = X + (size_t)row * CDIM;
  float v[5];
  float s = 0.f, s2 = 0.f;
#pragma unroll
  for (int i = 0; i < 5; ++i) {
    v[i] = (float)xr[threadIdx.x + 256 * i];
    s += v[i];
    s2 += v[i] * v[i];
  }
  const int lane = threadIdx.x & 63, wv = threadIdx.x >> 6;
#pragma unroll
  for (int off = 32; off > 0; off >>= 1) {
    s += __shfl_down(s, off);
    s2 += __shfl_down(s2, off);
  }
  __shared__ float red[8];
  if (lane == 0) { red[wv] = s; red[4 + wv] = s2; }
  __syncthreads();
  s = red[0] + red[1] + red[2] + red[3];
  s2 = red[4] + red[5] + red[6] + red[7];
  const float mu = s * (1.f / CDIM);
  const float var = s2 * (1.f / CDIM) - mu * mu;
  const float rstd = rsqrtf(fmaxf(var, 0.f) + 1e-5f);
#pragma unroll
  for (int i = 0; i < 5; ++i) {
    const int c = threadIdx.x + 256 * i;
    Y[(size_t)row * CDIM + c] =
        (__bf16)((v[i] - mu) * rstd * (float)gamma[c] + (float)beta[c]);
  }
}

// ---------------- GEMM: C[M,N] = A[M,K] @ Bt[N,K]^T (+bias, gelu, resid) ----
// 128x128 tile, BK=32, m97 structure: global_load_lds width=16, unpadded LDS.
__device__ __forceinline__ void gemm_tile(const __bf16* __restrict__ A,
                                          const __bf16* __restrict__ Bt,
                                          const __bf16* __restrict__ bias,
                                          const __bf16* __restrict__ resid,
                                          void* __restrict__ Cv,
                                          int M, int N, int K, int bm, int bn,
                                          bool gelu, int finalOut,
                                          const int* __restrict__ flag) {
  __shared__ __bf16 As[128 * 32];  // [m][k] unpadded: global_load_lds layout
  __shared__ __bf16 Bs[128 * 32];  // [n][k]
  const int tid = threadIdx.x;
  const int lane = tid & 63, wave = tid >> 6;
  const int wm = (wave >> 1) * 64, wn = (wave & 1) * 64;
  const int l16 = lane & 15, kq = (lane >> 4) << 3;
  const int lrow = lane >> 2;         // 0..15: row within 16-row segment
  const int lcol = (lane & 3) << 3;   // k-elems 0,8,16,24
  const int outbf = finalOut ? flag[0] : 1;

  f32x4 acc[4][4];
  const f32x4 zero = {0.f, 0.f, 0.f, 0.f};
#pragma unroll
  for (int i = 0; i < 4; ++i)
#pragma unroll
    for (int j = 0; j < 4; ++j) acc[i][j] = zero;

  for (int k0 = 0; k0 < K; k0 += 32) {
    // stage A+B tiles: 8 segments of 16 rows each; wave w owns segs w, w+4.
#pragma unroll
    for (int t = 0; t < 2; ++t) {
      const int seg = t * 4 + wave;
      int ga = bm * 128 + seg * 16 + lrow;
      if (ga > M - 1) ga = M - 1;  // clamp: garbage rows never stored
      GLOAD_LDS16(A + (size_t)ga * K + k0 + lcol, &As[seg * 16 * 32]);
      const int gb = bn * 128 + seg * 16 + lrow;  // N always multiple of 128
      GLOAD_LDS16(Bt + (size_t)gb * K + k0 + lcol, &Bs[seg * 16 * 32]);
    }
    __syncthreads();
    bf16x8 af[4], bfr[4];
#pragma unroll
    for (int i = 0; i < 4; ++i)
      af[i] = *(const bf16x8*)(&As[(wm + i * 16 + l16) * 32 + kq]);
#pragma unroll
    for (int j = 0; j < 4; ++j)
      bfr[j] = *(const bf16x8*)(&Bs[(wn + j * 16 + l16) * 32 + kq]);
#pragma unroll
    for (int i = 0; i < 4; ++i)
#pragma unroll
      for (int j = 0; j < 4; ++j)
        acc[i][j] = __builtin_amdgcn_mfma_f32_16x16x32_bf16(af[i], bfr[j],
                                                            acc[i][j], 0, 0, 0);
    __syncthreads();
  }

  // epilogue: D[row][col], col = lane&15, row = (lane>>4)*4 + r  (m89-verified)
  const int rq4 = (lane >> 4) * 4;
#pragma unroll
  for (int i = 0; i < 4; ++i) {
#pragma unroll
    for (int r = 0; r < 4; ++r) {
      const int grow = bm * 128 + wm + i * 16 + rq4 + r;
      if (grow >= M) continue;
#pragma unroll
      for (int j = 0; j < 4; ++j) {
        const int gcol = bn * 128 + wn + j * 16 + l16;
        float vv = acc[i][j][r];
        if (bias) vv += (float)bias[gcol];
        if (gelu) vv = 0.5f * vv * (1.f + erff(vv * 0.70710678118654752f));
        if (resid) vv += (float)resid[(size_t)grow * N + gcol];
        if (outbf) ((__bf16*)Cv)[(size_t)grow * N + gcol] = (__bf16)vv;
        else       ((float*)Cv)[(size_t)grow * N + gcol] = vv;
      }
    }
  }
}

__global__ __launch_bounds__(256) void gemm_kernel(const __bf16* __restrict__ A,
                                                   const __bf16* __restrict__ Bt,
                                                   const __bf16* __restrict__ bias,
                                                   const __bf16* __restrict__ resid,
                                                   void* __restrict__ C,
                                                   int M, int N, int K, int gelu,
                                                   int finalOut,
                                                   const int* __restrict__ flag) {
  gemm_tile(A, Bt, bias, resid, C, M, N, K, blockIdx.x, blockIdx.y, gelu != 0,
            finalOut, flag);
}

// fused Q/K/V: grid.y = 30 -> (which, bn)
__global__ __launch_bounds__(256) void gemm_qkv_kernel(const __bf16* __restrict__ A,
                                                       const __bf16* __restrict__ Wqt,
                                                       const __bf16* __restrict__ Wkt,
                                                       const __bf16* __restrict__ Wvt,
                                                       const __bf16* __restrict__ bq,
                                                       const __bf16* __restrict__ bv,
                                                       __bf16* __restrict__ Q,
                                                       __bf16* __restrict__ Ko,
                                                       __bf16* __restrict__ V,
                                                       const int* __restrict__ flag) {
  const int which = blockIdx.y / 10, bn = blockIdx.y % 10;
  const __bf16* Bt = (which == 0) ? Wqt : ((which == 1) ? Wkt : Wvt);
  const __bf16* bias = (which == 0) ? bq : ((which == 1) ? (const __bf16*)nullptr : bv);
  __bf16* C = (which == 0) ? Q : ((which == 1) ? Ko : V);
  gemm_tile(A, Bt, bias, nullptr, C, SEQ, CDIM, CDIM, blockIdx.x, bn, false, 0, flag);
}

// ---------------- MFMA flash attention ------------------------------------
// block = 1 head x 64 queries, 4 waves x 16 queries. Online softmax over
// 24 key-tiles of 64. QK^T: A=Q frags (regs), B=K tile (LDS). P round-trips
// through per-wave LDS (C-layout -> A-layout, m120 pattern). V pre-transposed
// globally: Vt[d][key] so B-operand reads are contiguous.
__global__ __launch_bounds__(256) void attn_mfma_kernel(
    const __bf16* __restrict__ Q,    // [SEQ][CDIM]
    const __bf16* __restrict__ Kk,   // [SEQ][CDIM]
    const __bf16* __restrict__ Vt,   // [CDIM][VTLD]
    __bf16* __restrict__ O) {        // [SEQ][CDIM]
  const int h = blockIdx.y;
  const int q0 = blockIdx.x * 64;
  const int tid = threadIdx.x;
  const int wave = tid >> 6, lane = tid & 63;
  const int l16 = lane & 15, quad = lane >> 4;

  __shared__ __bf16 Ks[64 * APAD];       // [key][d]
  __shared__ __bf16 Vs[64 * APAD];       // [d][key]
  __shared__ __bf16 Ps[4][16 * APAD];    // per-wave P: [q][key]

  // Q fragments (A-operand): m = l16 -> query, k = quad*8+j (+32 for ks=1)
  bf16x8 qf[2];
  {
    int q = q0 + wave * 16 + l16;
    if (q > SEQ - 1) q = SEQ - 1;
    const __bf16* qp = Q + (size_t)q * CDIM + h * DHEAD + quad * 8;
    qf[0] = *(const bf16x8*)(qp);
    qf[1] = *(const bf16x8*)(qp + 32);
  }

  f32x4 oacc[4];
  const f32x4 zero = {0.f, 0.f, 0.f, 0.f};
#pragma unroll
  for (int jt = 0; jt < 4; ++jt) oacc[jt] = zero;
  float mrow[4], lrow[4];
#pragma unroll
  for (int r = 0; r < 4; ++r) { mrow[r] = -30000.f; lrow[r] = 0.f; }

  const int srow = tid >> 2;         // staging row 0..63
  const int scol = (tid & 3) << 4;   // staging col 0,16,32,48

  const __bf16* Kbase = Kk + h * DHEAD;
  const __bf16* Vbase = Vt + (size_t)(h * DHEAD + srow) * VTLD;

  for (int kt = 0; kt < 24; ++kt) {
    const int key0 = kt * 64;
    __syncthreads();  // prior tile's reads complete
    {
      int gk = key0 + srow;
      if (gk > SEQ - 1) gk = SEQ - 1;
      const __bf16* kp = Kbase + (size_t)gk * CDIM + scol;
      *(bf16x8*)(&Ks[srow * APAD + scol]) = *(const bf16x8*)(kp);
      *(bf16x8*)(&Ks[srow * APAD + scol + 8]) = *(const bf16x8*)(kp + 8);
      const __bf16* vp = Vbase + key0 + scol;
      *(bf16x8*)(&Vs[srow * APAD + scol]) = *(const bf16x8*)(vp);
      *(bf16x8*)(&Vs[srow * APAD + scol + 8]) = *(const bf16x8*)(vp + 8);
    }
    __syncthreads();

    // --- S = Q K^T (C-layout: row=q=quad*4+r, col=key=jt*16+l16) ---
    f32x4 s[4];
#pragma unroll
    for (int jt = 0; jt < 4; ++jt) s[jt] = zero;
#pragma unroll
    for (int jt = 0; jt < 4; ++jt)
#pragma unroll
      for (int ks = 0; ks < 2; ++ks) {
        const bf16x8 kf = *(const bf16x8*)(&Ks[(jt * 16 + l16) * APAD + ks * 32 + quad * 8]);
        s[jt] = __builtin_amdgcn_mfma_f32_16x16x32_bf16(qf[ks], kf, s[jt], 0, 0, 0);
      }

    // scale + mask
#pragma unroll
    for (int jt = 0; jt < 4; ++jt) {
      const int key = key0 + jt * 16 + l16;
#pragma unroll
      for (int r = 0; r < 4; ++r) {
        float sv = s[jt][r] * 0.125f;
        if (key >= SEQ) sv = -30000.f;
        s[jt][r] = sv;
      }
    }

    // online softmax update
#pragma unroll
    for (int r = 0; r < 4; ++r) {
      float tmax = fmaxf(fmaxf(s[0][r], s[1][r]), fmaxf(s[2][r], s[3][r]));
#pragma unroll
      for (int off = 8; off > 0; off >>= 1) tmax = fmaxf(tmax, __shfl_xor(tmax, off));
      const float mnew = fmaxf(mrow[r], tmax);
      const float alpha = __expf(mrow[r] - mnew);
      mrow[r] = mnew;
      lrow[r] *= alpha;
#pragma unroll
      for (int jt = 0; jt < 4; ++jt) oacc[jt][r] *= alpha;
#pragma unroll
      for (int jt = 0; jt < 4; ++jt) {
        const float p = __expf(s[jt][r] - mnew);
        lrow[r] += p;
        Ps[wave][(quad * 4 + r) * APAD + jt * 16 + l16] = (__bf16)p;
      }
    }
    __syncthreads();  // P visible (per-wave region; barrier also orders Ks/Vs)

    // --- O += P V (A=P from LDS, B=Vs; D rows match softmax state rows) ---
    bf16x8 pf[2];
    pf[0] = *(const bf16x8*)(&Ps[wave][l16 * APAD + quad * 8]);
    pf[1] = *(const bf16x8*)(&Ps[wave][l16 * APAD + 32 + quad * 8]);
#pragma unroll
    for (int jt = 0; jt < 4; ++jt)
#pragma unroll
      for (int ks = 0; ks < 2; ++ks) {
        const bf16x8 vf = *(const bf16x8*)(&Vs[(jt * 16 + l16) * APAD + ks * 32 + quad * 8]);
        oacc[jt] = __builtin_amdgcn_mfma_f32_16x16x32_bf16(pf[ks], vf, oacc[jt], 0, 0, 0);
      }
  }

  // finalize: total l per row, normalize, store
#pragma unroll
  for (int r = 0; r < 4; ++r) {
    float lt = lrow[r];
#pragma unroll
    for (int off = 8; off > 0; off >>= 1) lt += __shfl_xor(lt, off);
    const float inv = 1.f / lt;
    const int q = q0 + wave * 16 + quad * 4 + r;
    if (q < SEQ) {
#pragma unroll
      for (int jt = 0; jt < 4; ++jt)
        O[(size_t)q * CDIM + h * DHEAD + jt * 16 + l16] = (__bf16)(oacc[jt][r] * inv);
    }
  }
}

// ---------------- launch ----------------
extern "C" void kernel_launch(void* const* d_in, const int* in_sizes, int n_in,
                              void* d_out, int out_size, void* d_ws, size_t ws_size,
                              hipStream_t stream) {
  const void* x   = d_in[0];
  const void* Wq  = d_in[1];
  const void* bq  = d_in[2];
  const void* Wk  = d_in[3];
  const void* Wv  = d_in[4];
  const void* bv  = d_in[5];
  const void* Wo  = d_in[6];
  const void* bo  = d_in[7];
  const void* g1  = d_in[8];
  const void* be1 = d_in[9];
  const void* g2  = d_in[10];
  const void* be2 = d_in[11];
  const void* W1  = d_in[12];
  const void* bm1 = d_in[13];
  const void* W2  = d_in[14];
  const void* bm2 = d_in[15];

  char* ws = (char*)d_ws;
  size_t off = 0;
  auto alloc = [&](size_t elems) {
    __bf16* p = (__bf16*)(ws + off);
    off += elems * sizeof(__bf16);
    return p;
  };
  __bf16* Wqt = alloc((size_t)CDIM * CDIM);
  __bf16* Wkt = alloc((size_t)CDIM * CDIM);
  __bf16* Wvt = alloc((size_t)CDIM * CDIM);
  __bf16* Wot = alloc((size_t)CDIM * CDIM);
  __bf16* W1t = alloc((size_t)CDIM * NMLP);
  __bf16* W2t = alloc((size_t)CDIM * NMLP);
  __bf16* hb  = alloc((size_t)SEQ * CDIM);   // h / attn-out
  __bf16* qb  = alloc((size_t)SEQ * CDIM);   // q / x1
  __bf16* kb  = alloc((size_t)SEQ * CDIM);   // k / h2
  __bf16* vb  = alloc((size_t)SEQ * CDIM);   // v
  __bf16* mb  = alloc((size_t)SEQ * NMLP);   // mlp hidden; first 1280*VTLD = Vt
  __bf16* xb  = alloc((size_t)SEQ * CDIM);   // x converted to bf16
  __bf16* pb  = alloc(16384);                // packed small params
  int* flag = (int*)(ws + off);
  __bf16* vtb = mb;  // Vt[CDIM][VTLD] lives in mb region (dead until MLP1)

  __bf16* bq_b  = pb + 0;
  __bf16* bv_b  = pb + 1280;
  __bf16* bo_b  = pb + 2560;
  __bf16* g1_b  = pb + 3840;
  __bf16* be1_b = pb + 5120;
  __bf16* g2_b  = pb + 6400;
  __bf16* be2_b = pb + 7680;
  __bf16* b1_b  = pb + 8960;   // 5120
  __bf16* b2_b  = pb + 14080;

  detect_kernel<<<1, 256, 0, stream>>>((const unsigned int*)x, flag);

  convert_kernel<<<960, 256, 0, stream>>>(x, xb, SEQ * CDIM, flag);
  convert_kernel<<<5, 256, 0, stream>>>(bq, bq_b, CDIM, flag);
  convert_kernel<<<5, 256, 0, stream>>>(bv, bv_b, CDIM, flag);
  convert_kernel<<<5, 256, 0, stream>>>(bo, bo_b, CDIM, flag);
  convert_kernel<<<5, 256, 0, stream>>>(g1, g1_b, CDIM, flag);
  convert_kernel<<<5, 256, 0, stream>>>(be1, be1_b, CDIM, flag);
  convert_kernel<<<5, 256, 0, stream>>>(g2, g2_b, CDIM, flag);
  convert_kernel<<<5, 256, 0, stream>>>(be2, be2_b, CDIM, flag);
  convert_kernel<<<20, 256, 0, stream>>>(bm1, b1_b, NMLP, flag);
  convert_kernel<<<5, 256, 0, stream>>>(bm2, b2_b, CDIM, flag);

  const dim3 tb(32, 8);
  transpose_kernel<<<dim3(40, 40), tb, 0, stream>>>(Wq, Wqt, CDIM, CDIM, flag);
  transpose_kernel<<<dim3(40, 40), tb, 0, stream>>>(Wk, Wkt, CDIM, CDIM, flag);
  transpose_kernel<<<dim3(40, 40), tb, 0, stream>>>(Wv, Wvt, CDIM, CDIM, flag);
  transpose_kernel<<<dim3(40, 40), tb, 0, stream>>>(Wo, Wot, CDIM, CDIM, flag);
  transpose_kernel<<<dim3(160, 40), tb, 0, stream>>>(W1, W1t, CDIM, NMLP, flag);
  transpose_kernel<<<dim3(40, 160), tb, 0, stream>>>(W2, W2t, NMLP, CDIM, flag);

  ln_kernel<<<SEQ, 256, 0, stream>>>(xb, g1_b, be1_b, hb);
  gemm_qkv_kernel<<<dim3(12, 30), 256, 0, stream>>>(hb, Wqt, Wkt, Wvt, bq_b, bv_b,
                                                    qb, kb, vb, flag);
  // Vt = vb^T  (into mb region; mb not used until MLP1)
  transpose_act_kernel<<<dim3(40, 47), tb, 0, stream>>>(vb, vtb);
  attn_mfma_kernel<<<dim3(24, NHEAD), 256, 0, stream>>>(qb, kb, vtb, hb);
  // x1 = x + attn @ Wo + bo   -> qb
  gemm_kernel<<<dim3(12, 10), 256, 0, stream>>>(hb, Wot, bo_b, xb, qb,
                                                SEQ, CDIM, CDIM, 0, 0, flag);
  // h2 = LN2(x1) -> kb
  ln_kernel<<<SEQ, 256, 0, stream>>>(qb, g2_b, be2_b, kb);
  // m = gelu(h2 @ W1 + b1)   (overwrites vtb; attention already done)
  gemm_kernel<<<dim3(12, 40), 256, 0, stream>>>(kb, W1t, b1_b, nullptr, mb,
                                                SEQ, NMLP, CDIM, 1, 0, flag);
  // out = x1 + m @ W2 + b2  (output dtype per flag)
  gemm_kernel<<<dim3(12, 10), 256, 0, stream>>>(mb, W2t, b2_b, qb, d_out,
                                                SEQ, CDIM, NMLP, 0, 1, flag);
}

// Round 4
// 411.389 us; speedup vs baseline: 2.3907x; 1.3838x over previous
//
#include <hip/hip_runtime.h>
#include <hip/hip_bf16.h>
#include <math.h>

typedef __bf16 bf16x8 __attribute__((ext_vector_type(8)));
typedef float f32x4 __attribute__((ext_vector_type(4)));

#define SEQ 1500
#define CDIM 1280
#define NHEAD 20
#define DHEAD 64
#define NMLP 5120
#define QKVN 3840
#define VTLD 1504   // leading dim of transposed V (47*32)
#define APAD 72     // attention LDS stride

#define GLOAD_LDS16(gp, lp)                                                    \
  __builtin_amdgcn_global_load_lds(                                            \
      (const __attribute__((address_space(1))) unsigned int*)(gp),             \
      (__attribute__((address_space(3))) unsigned int*)(lp), 16, 0, 0)

// ---------------- dtype detection: bf16 (flag=1) vs fp32 (flag=0) ----------
__global__ void detect_kernel(const unsigned int* __restrict__ xw,
                              int* __restrict__ flag) {
  __shared__ int cnt[256];
  const unsigned int w = xw[threadIdx.x];
  const unsigned int e = (w >> 7) & 0xFF;
  cnt[threadIdx.x] = (e >= 100 && e <= 150) ? 1 : 0;
  __syncthreads();
  for (int s = 128; s > 0; s >>= 1) {
    if (threadIdx.x < (unsigned)s) cnt[threadIdx.x] += cnt[threadIdx.x + s];
    __syncthreads();
  }
  if (threadIdx.x == 0) flag[0] = (cnt[0] >= 160) ? 1 : 0;
}

// ---------------- x convert to bf16 (dtype-adaptive) -----------------------
__global__ __launch_bounds__(256) void convert_kernel(const void* __restrict__ src,
                                                      __bf16* __restrict__ dst,
                                                      int n, const int* __restrict__ flag) {
  const int isbf = flag[0];
  int i = blockIdx.x * 256 + threadIdx.x;
  const int stride = gridDim.x * 256;
  if (isbf) {
    const __bf16* s = (const __bf16*)src;
    for (; i < n; i += stride) dst[i] = s[i];
  } else {
    const float* s = (const float*)src;
    for (; i < n; i += stride) dst[i] = (__bf16)s[i];
  }
}

// ---------------- pack all small params into pb (bf16) ---------------------
// layout: [0,3840) qkvbias (bq|0|bv) | 3840 bo | 5120 g1 | 6400 be1 |
//         7680 g2 | 8960 be2 | 10240 b1(5120) | 15360 b2 | total 16640
__global__ __launch_bounds__(256) void pack_params_kernel(
    const void* bq, const void* bv, const void* bo, const void* g1,
    const void* be1, const void* g2, const void* be2, const void* b1,
    const void* b2, __bf16* __restrict__ pb, const int* __restrict__ flag) {
  const int isbf = flag[0];
  const int i = blockIdx.x * 256 + threadIdx.x;
  if (i >= 16640) return;
  auto ld = [&](const void* p, int j) -> float {
    return isbf ? (float)((const __bf16*)p)[j] : ((const float*)p)[j];
  };
  float v;
  if (i < 3840) {
    if (i < 1280) v = ld(bq, i);
    else if (i < 2560) v = 0.f;
    else v = ld(bv, i - 2560);
  } else if (i < 5120) v = ld(bo, i - 3840);
  else if (i < 6400) v = ld(g1, i - 5120);
  else if (i < 7680) v = ld(be1, i - 6400);
  else if (i < 8960) v = ld(g2, i - 7680);
  else if (i < 10240) v = ld(be2, i - 8960);
  else if (i < 15360) v = ld(b1, i - 10240);
  else v = ld(b2, i - 15360);
  pb[i] = (__bf16)v;
}

// ---------------- weight transpose: in (K,N) -> out (N,K), bf16 out --------
__device__ __forceinline__ void transpose_body(const void* in, __bf16* out,
                                               int K, int N, int isbf) {
  __shared__ __bf16 t[32][33];
  const int tx = threadIdx.x, ty = threadIdx.y;
  const int n0 = blockIdx.x * 32, k0 = blockIdx.y * 32;
  if (isbf) {
    const __bf16* s = (const __bf16*)in;
#pragma unroll
    for (int i = ty; i < 32; i += 8)
      t[i][tx] = s[(size_t)(k0 + i) * N + n0 + tx];
  } else {
    const float* s = (const float*)in;
#pragma unroll
    for (int i = ty; i < 32; i += 8)
      t[i][tx] = (__bf16)s[(size_t)(k0 + i) * N + n0 + tx];
  }
  __syncthreads();
#pragma unroll
  for (int i = ty; i < 32; i += 8)
    out[(size_t)(n0 + i) * K + k0 + tx] = t[tx][i];
}

__global__ __launch_bounds__(256) void transpose_kernel(const void* __restrict__ in,
                                                        __bf16* __restrict__ out,
                                                        int K, int N,
                                                        const int* __restrict__ flag) {
  transpose_body(in, out, K, N, flag[0]);
}

// fused Wq/Wk/Wv transpose -> contiguous Wqkvt[3840][1280]
__global__ __launch_bounds__(256) void transpose3_kernel(const void* __restrict__ Wq,
                                                         const void* __restrict__ Wk,
                                                         const void* __restrict__ Wv,
                                                         __bf16* __restrict__ out,
                                                         const int* __restrict__ flag) {
  const void* in = blockIdx.z == 0 ? Wq : (blockIdx.z == 1 ? Wk : Wv);
  transpose_body(in, out + (size_t)blockIdx.z * CDIM * CDIM, CDIM, CDIM, flag[0]);
}

// ---------------- activation transpose: [SEQ][.] -> [N][VTLD] --------------
__global__ __launch_bounds__(256) void transpose_act_kernel(const __bf16* __restrict__ in,
                                                            __bf16* __restrict__ out,
                                                            int istride) {
  __shared__ __bf16 t[32][33];
  const int tx = threadIdx.x, ty = threadIdx.y;
  const int n0 = blockIdx.x * 32, k0 = blockIdx.y * 32;
#pragma unroll
  for (int i = ty; i < 32; i += 8) {
    const int k = k0 + i;
    t[i][tx] = (k < SEQ) ? in[(size_t)k * istride + n0 + tx] : (__bf16)0.f;
  }
  __syncthreads();
#pragma unroll
  for (int i = ty; i < 32; i += 8) {
    const int kk = k0 + tx;
    if (kk < VTLD) out[(size_t)(n0 + i) * VTLD + kk] = t[tx][i];
  }
}

// ---------------- layernorm: 1 block per row, 1280 = 5*256 ----------------
__global__ __launch_bounds__(256) void ln_kernel(const __bf16* __restrict__ X,
                                                 const __bf16* __restrict__ gamma,
                                                 const __bf16* __restrict__ beta,
                                                 __bf16* __restrict__ Y) {
  const int row = blockIdx.x;
  const __bf16* xr = X + (size_t)row * CDIM;
  float v[5];
  float s = 0.f, s2 = 0.f;
#pragma unroll
  for (int i = 0; i < 5; ++i) {
    v[i] = (float)xr[threadIdx.x + 256 * i];
    s += v[i];
    s2 += v[i] * v[i];
  }
  const int lane = threadIdx.x & 63, wv = threadIdx.x >> 6;
#pragma unroll
  for (int off = 32; off > 0; off >>= 1) {
    s += __shfl_down(s, off);
    s2 += __shfl_down(s2, off);
  }
  __shared__ float red[8];
  if (lane == 0) { red[wv] = s; red[4 + wv] = s2; }
  __syncthreads();
  s = red[0] + red[1] + red[2] + red[3];
  s2 = red[4] + red[5] + red[6] + red[7];
  const float mu = s * (1.f / CDIM);
  const float var = s2 * (1.f / CDIM) - mu * mu;
  const float rstd = rsqrtf(fmaxf(var, 0.f) + 1e-5f);
#pragma unroll
  for (int i = 0; i < 5; ++i) {
    const int c = threadIdx.x + 256 * i;
    Y[(size_t)row * CDIM + c] =
        (__bf16)((v[i] - mu) * rstd * (float)gamma[c] + (float)beta[c]);
  }
}

// ---------------- GEMM 64x128 tile, BK=32, m97 staging ---------------------
// grid (Mtiles, Ntiles, nsplit). nsplit>1: fp32 partials to Cv + z*M*N,
// no epilogue. nsplit==1: bf16 out with bias (+gelu).
__global__ __launch_bounds__(256) void gemm64_kernel(
    const __bf16* __restrict__ A, const __bf16* __restrict__ Bt,
    const __bf16* __restrict__ bias, void* __restrict__ Cv,
    int M, int N, int K, int KS, int gelu, int nsplit) {
  __shared__ __bf16 As[64 * 32];
  __shared__ __bf16 Bs[128 * 32];
  const int bm = blockIdx.x, bn = blockIdx.y, sz = blockIdx.z;
  const int tid = threadIdx.x;
  const int lane = tid & 63, wave = tid >> 6;
  const int l16 = lane & 15, kq = (lane >> 4) << 3;
  const int lrow = lane >> 2, lcol = (lane & 3) << 3;
  const int wn = wave * 32;

  f32x4 acc[4][2];
  const f32x4 zero = {0.f, 0.f, 0.f, 0.f};
#pragma unroll
  for (int i = 0; i < 4; ++i)
#pragma unroll
    for (int j = 0; j < 2; ++j) acc[i][j] = zero;

  const int kbeg = sz * KS;
  int kend = kbeg + KS;
  if (kend > K) kend = K;

  for (int k0 = kbeg; k0 < kend; k0 += 32) {
    {
      int ga = bm * 64 + wave * 16 + lrow;
      if (ga > M - 1) ga = M - 1;  // clamp: garbage rows never stored
      GLOAD_LDS16(A + (size_t)ga * K + k0 + lcol, &As[wave * 16 * 32]);
    }
#pragma unroll
    for (int t = 0; t < 2; ++t) {
      const int seg = t * 4 + wave;
      const int gb = bn * 128 + seg * 16 + lrow;  // N multiple of 128
      GLOAD_LDS16(Bt + (size_t)gb * K + k0 + lcol, &Bs[seg * 16 * 32]);
    }
    __syncthreads();
    bf16x8 af[4], bfr[2];
#pragma unroll
    for (int i = 0; i < 4; ++i)
      af[i] = *(const bf16x8*)(&As[(i * 16 + l16) * 32 + kq]);
#pragma unroll
    for (int j = 0; j < 2; ++j)
      bfr[j] = *(const bf16x8*)(&Bs[(wn + j * 16 + l16) * 32 + kq]);
#pragma unroll
    for (int i = 0; i < 4; ++i)
#pragma unroll
      for (int j = 0; j < 2; ++j)
        acc[i][j] = __builtin_amdgcn_mfma_f32_16x16x32_bf16(af[i], bfr[j],
                                                            acc[i][j], 0, 0, 0);
    __syncthreads();
  }

  // epilogue: D[row][col], col = lane&15, row = (lane>>4)*4 + r
  const int rq4 = (lane >> 4) * 4;
  if (nsplit > 1) {
    float* P = (float*)Cv + (size_t)sz * M * N;
#pragma unroll
    for (int i = 0; i < 4; ++i)
#pragma unroll
      for (int r = 0; r < 4; ++r) {
        const int grow = bm * 64 + i * 16 + rq4 + r;
        if (grow >= M) continue;
#pragma unroll
        for (int j = 0; j < 2; ++j) {
          const int gcol = bn * 128 + wn + j * 16 + l16;
          P[(size_t)grow * N + gcol] = acc[i][j][r];
        }
      }
  } else {
    __bf16* Cb = (__bf16*)Cv;
#pragma unroll
    for (int i = 0; i < 4; ++i)
#pragma unroll
      for (int r = 0; r < 4; ++r) {
        const int grow = bm * 64 + i * 16 + rq4 + r;
        if (grow >= M) continue;
#pragma unroll
        for (int j = 0; j < 2; ++j) {
          const int gcol = bn * 128 + wn + j * 16 + l16;
          float vv = acc[i][j][r];
          if (bias) vv += (float)bias[gcol];
          if (gelu) vv = 0.5f * vv * (1.f + erff(vv * 0.70710678118654752f));
          Cb[(size_t)grow * N + gcol] = (__bf16)vv;
        }
      }
  }
}

// ---------------- split-K reduce: out = resid + sum(P) + bias --------------
__global__ __launch_bounds__(256) void reduce_kernel(
    const float* __restrict__ P, const __bf16* __restrict__ bias,
    const __bf16* __restrict__ resid, void* __restrict__ out,
    int MN, int N, int S, int useflag, const int* __restrict__ flag) {
  const int i = blockIdx.x * 256 + threadIdx.x;
  if (i >= MN) return;
  float v = 0.f;
  for (int s = 0; s < S; ++s) v += P[(size_t)s * MN + i];
  v += (float)bias[i % N];
  if (resid) v += (float)resid[i];
  const int outbf = useflag ? flag[0] : 1;
  if (outbf) ((__bf16*)out)[i] = (__bf16)v;
  else       ((float*)out)[i] = v;
}

// ---------------- MFMA flash attention (Q/K from fused buffer, stride rs) --
__global__ __launch_bounds__(256) void attn_mfma_kernel(
    const __bf16* __restrict__ Q,    // fused base (+0), row stride rs
    const __bf16* __restrict__ Kk,   // fused base + 1280, row stride rs
    const __bf16* __restrict__ Vt,   // [CDIM][VTLD]
    __bf16* __restrict__ O,          // [SEQ][CDIM]
    int rs) {
  const int h = blockIdx.y;
  const int q0 = blockIdx.x * 64;
  const int tid = threadIdx.x;
  const int wave = tid >> 6, lane = tid & 63;
  const int l16 = lane & 15, quad = lane >> 4;

  __shared__ __bf16 Ks[64 * APAD];
  __shared__ __bf16 Vs[64 * APAD];
  __shared__ __bf16 Ps[4][16 * APAD];

  bf16x8 qf[2];
  {
    int q = q0 + wave * 16 + l16;
    if (q > SEQ - 1) q = SEQ - 1;
    const __bf16* qp = Q + (size_t)q * rs + h * DHEAD + quad * 8;
    qf[0] = *(const bf16x8*)(qp);
    qf[1] = *(const bf16x8*)(qp + 32);
  }

  f32x4 oacc[4];
  const f32x4 zero = {0.f, 0.f, 0.f, 0.f};
#pragma unroll
  for (int jt = 0; jt < 4; ++jt) oacc[jt] = zero;
  float mrow[4], lrow[4];
#pragma unroll
  for (int r = 0; r < 4; ++r) { mrow[r] = -30000.f; lrow[r] = 0.f; }

  const int srow = tid >> 2;
  const int scol = (tid & 3) << 4;

  const __bf16* Kbase = Kk + h * DHEAD;
  const __bf16* Vbase = Vt + (size_t)(h * DHEAD + srow) * VTLD;

  for (int kt = 0; kt < 24; ++kt) {
    const int key0 = kt * 64;
    __syncthreads();
    {
      int gk = key0 + srow;
      if (gk > SEQ - 1) gk = SEQ - 1;
      const __bf16* kp = Kbase + (size_t)gk * rs + scol;
      *(bf16x8*)(&Ks[srow * APAD + scol]) = *(const bf16x8*)(kp);
      *(bf16x8*)(&Ks[srow * APAD + scol + 8]) = *(const bf16x8*)(kp + 8);
      const __bf16* vp = Vbase + key0 + scol;
      *(bf16x8*)(&Vs[srow * APAD + scol]) = *(const bf16x8*)(vp);
      *(bf16x8*)(&Vs[srow * APAD + scol + 8]) = *(const bf16x8*)(vp + 8);
    }
    __syncthreads();

    f32x4 s[4];
#pragma unroll
    for (int jt = 0; jt < 4; ++jt) s[jt] = zero;
#pragma unroll
    for (int jt = 0; jt < 4; ++jt)
#pragma unroll
      for (int ks = 0; ks < 2; ++ks) {
        const bf16x8 kf = *(const bf16x8*)(&Ks[(jt * 16 + l16) * APAD + ks * 32 + quad * 8]);
        s[jt] = __builtin_amdgcn_mfma_f32_16x16x32_bf16(qf[ks], kf, s[jt], 0, 0, 0);
      }

#pragma unroll
    for (int jt = 0; jt < 4; ++jt) {
      const int key = key0 + jt * 16 + l16;
#pragma unroll
      for (int r = 0; r < 4; ++r) {
        float sv = s[jt][r] * 0.125f;
        if (key >= SEQ) sv = -30000.f;
        s[jt][r] = sv;
      }
    }

#pragma unroll
    for (int r = 0; r < 4; ++r) {
      float tmax = fmaxf(fmaxf(s[0][r], s[1][r]), fmaxf(s[2][r], s[3][r]));
#pragma unroll
      for (int off = 8; off > 0; off >>= 1) tmax = fmaxf(tmax, __shfl_xor(tmax, off));
      const float mnew = fmaxf(mrow[r], tmax);
      const float alpha = __expf(mrow[r] - mnew);
      mrow[r] = mnew;
      lrow[r] *= alpha;
#pragma unroll
      for (int jt = 0; jt < 4; ++jt) oacc[jt][r] *= alpha;
#pragma unroll
      for (int jt = 0; jt < 4; ++jt) {
        const float p = __expf(s[jt][r] - mnew);
        lrow[r] += p;
        Ps[wave][(quad * 4 + r) * APAD + jt * 16 + l16] = (__bf16)p;
      }
    }
    __syncthreads();

    bf16x8 pf[2];
    pf[0] = *(const bf16x8*)(&Ps[wave][l16 * APAD + quad * 8]);
    pf[1] = *(const bf16x8*)(&Ps[wave][l16 * APAD + 32 + quad * 8]);
#pragma unroll
    for (int jt = 0; jt < 4; ++jt)
#pragma unroll
      for (int ks = 0; ks < 2; ++ks) {
        const bf16x8 vf = *(const bf16x8*)(&Vs[(jt * 16 + l16) * APAD + ks * 32 + quad * 8]);
        oacc[jt] = __builtin_amdgcn_mfma_f32_16x16x32_bf16(pf[ks], vf, oacc[jt], 0, 0, 0);
      }
  }

#pragma unroll
  for (int r = 0; r < 4; ++r) {
    float lt = lrow[r];
#pragma unroll
    for (int off = 8; off > 0; off >>= 1) lt += __shfl_xor(lt, off);
    const float inv = 1.f / lt;
    const int q = q0 + wave * 16 + quad * 4 + r;
    if (q < SEQ) {
#pragma unroll
      for (int jt = 0; jt < 4; ++jt)
        O[(size_t)q * CDIM + h * DHEAD + jt * 16 + l16] = (__bf16)(oacc[jt][r] * inv);
    }
  }
}

// ---------------- launch ----------------
extern "C" void kernel_launch(void* const* d_in, const int* in_sizes, int n_in,
                              void* d_out, int out_size, void* d_ws, size_t ws_size,
                              hipStream_t stream) {
  const void* x   = d_in[0];
  const void* Wq  = d_in[1];
  const void* bq  = d_in[2];
  const void* Wk  = d_in[3];
  const void* Wv  = d_in[4];
  const void* bv  = d_in[5];
  const void* Wo  = d_in[6];
  const void* bo  = d_in[7];
  const void* g1  = d_in[8];
  const void* be1 = d_in[9];
  const void* g2  = d_in[10];
  const void* be2 = d_in[11];
  const void* W1  = d_in[12];
  const void* bm1 = d_in[13];
  const void* W2  = d_in[14];
  const void* bm2 = d_in[15];

  char* ws = (char*)d_ws;
  size_t off = 0;
  auto alloc = [&](size_t elems) {
    __bf16* p = (__bf16*)(ws + off);
    off += elems * sizeof(__bf16);
    return p;
  };
  __bf16* Wqkvt = alloc((size_t)QKVN * CDIM);   // fused Wq^T|Wk^T|Wv^T
  __bf16* Wot   = alloc((size_t)CDIM * CDIM);
  __bf16* W1t   = alloc((size_t)CDIM * NMLP);
  __bf16* W2t   = alloc((size_t)CDIM * NMLP);
  __bf16* qkvb  = alloc((size_t)SEQ * QKVN);    // fused q|k|v; later x1|h2
  __bf16* hb    = alloc((size_t)SEQ * CDIM);    // ln1 out / attn out
  __bf16* xb    = alloc((size_t)SEQ * CDIM);    // x as bf16
  __bf16* mb    = alloc((size_t)SEQ * NMLP);    // mlp hidden; head = Vt
  __bf16* pb    = alloc(20480);                 // packed params
  off = (off + 15) & ~(size_t)15;
  float* pscr = (float*)(ws + off);             // split-K partials, 2 x M x N
  off += (size_t)2 * SEQ * CDIM * sizeof(float);
  int* flag = (int*)(ws + off);

  __bf16* vtb  = mb;                 // Vt[CDIM][VTLD] (dead before MLP1)
  __bf16* x1b  = qkvb;               // x1 (qkv dead after attention)
  __bf16* h2b  = qkvb + (size_t)SEQ * CDIM;  // ln2 out

  __bf16* qkvbias = pb + 0;
  __bf16* bo_b  = pb + 3840;
  __bf16* g1_b  = pb + 5120;
  __bf16* be1_b = pb + 6400;
  __bf16* g2_b  = pb + 7680;
  __bf16* be2_b = pb + 8960;
  __bf16* b1_b  = pb + 10240;
  __bf16* b2_b  = pb + 15360;

  detect_kernel<<<1, 256, 0, stream>>>((const unsigned int*)x, flag);
  convert_kernel<<<960, 256, 0, stream>>>(x, xb, SEQ * CDIM, flag);
  pack_params_kernel<<<65, 256, 0, stream>>>(bq, bv, bo, g1, be1, g2, be2,
                                             bm1, bm2, pb, flag);

  const dim3 tb(32, 8);
  transpose3_kernel<<<dim3(40, 40, 3), tb, 0, stream>>>(Wq, Wk, Wv, Wqkvt, flag);
  transpose_kernel<<<dim3(40, 40), tb, 0, stream>>>(Wo, Wot, CDIM, CDIM, flag);
  transpose_kernel<<<dim3(160, 40), tb, 0, stream>>>(W1, W1t, CDIM, NMLP, flag);
  transpose_kernel<<<dim3(40, 160), tb, 0, stream>>>(W2, W2t, NMLP, CDIM, flag);

  // h = LN1(x)
  ln_kernel<<<SEQ, 256, 0, stream>>>(xb, g1_b, be1_b, hb);
  // qkv = h @ Wqkv^T + (bq|0|bv)   [1500][3840]
  gemm64_kernel<<<dim3(24, 30, 1), 256, 0, stream>>>(
      hb, Wqkvt, qkvbias, qkvb, SEQ, QKVN, CDIM, CDIM, 0, 1);
  // Vt = V^T (V = qkvb col-block 2)
  transpose_act_kernel<<<dim3(40, 47), tb, 0, stream>>>(qkvb + 2560, vtb, QKVN);
  // attn -> hb
  attn_mfma_kernel<<<dim3(24, NHEAD), 256, 0, stream>>>(
      qkvb, qkvb + 1280, vtb, hb, QKVN);
  // attn @ Wo (split-K=2, fp32 partials)
  gemm64_kernel<<<dim3(24, 10, 2), 256, 0, stream>>>(
      hb, Wot, nullptr, pscr, SEQ, CDIM, CDIM, 640, 0, 2);
  // x1 = x + partials + bo
  reduce_kernel<<<7500, 256, 0, stream>>>(pscr, bo_b, xb, x1b,
                                          SEQ * CDIM, CDIM, 2, 0, flag);
  // h2 = LN2(x1)
  ln_kernel<<<SEQ, 256, 0, stream>>>(x1b, g2_b, be2_b, h2b);
  // m = gelu(h2 @ W1 + b1)
  gemm64_kernel<<<dim3(24, 40, 1), 256, 0, stream>>>(
      h2b, W1t, b1_b, mb, SEQ, NMLP, CDIM, CDIM, 1, 1);
  // m @ W2 (split-K=2)
  gemm64_kernel<<<dim3(24, 10, 2), 256, 0, stream>>>(
      mb, W2t, nullptr, pscr, SEQ, CDIM, NMLP, 2560, 0, 2);
  // out = x1 + partials + b2 (dtype per flag)
  reduce_kernel<<<7500, 256, 0, stream>>>(pscr, b2_b, x1b, d_out,
                                          SEQ * CDIM, CDIM, 2, 1, flag);
}

// Round 5
// 377.234 us; speedup vs baseline: 2.6071x; 1.0905x over previous
//
#include <hip/hip_runtime.h>
#include <hip/hip_bf16.h>
#include <math.h>

typedef __bf16 bf16x8 __attribute__((ext_vector_type(8)));
typedef float f32x4 __attribute__((ext_vector_type(4)));

#define SEQ 1500
#define CDIM 1280
#define NHEAD 20
#define DHEAD 64
#define NMLP 5120
#define QKVN 3840
#define VTLD 1504   // leading dim of transposed V (47*32)
#define APAD 68     // attention LDS stride (34 dwords ≡ 2 mod 32: bank-spread)

#define GLOAD_LDS16(gp, lp)                                                    \
  __builtin_amdgcn_global_load_lds(                                            \
      (const __attribute__((address_space(1))) unsigned int*)(gp),             \
      (__attribute__((address_space(3))) unsigned int*)(lp), 16, 0, 0)

// ---------------- dtype detection: bf16 (flag=1) vs fp32 (flag=0) ----------
__global__ void detect_kernel(const unsigned int* __restrict__ xw,
                              int* __restrict__ flag) {
  __shared__ int cnt[256];
  const unsigned int w = xw[threadIdx.x];
  const unsigned int e = (w >> 7) & 0xFF;
  cnt[threadIdx.x] = (e >= 100 && e <= 150) ? 1 : 0;
  __syncthreads();
  for (int s = 128; s > 0; s >>= 1) {
    if (threadIdx.x < (unsigned)s) cnt[threadIdx.x] += cnt[threadIdx.x + s];
    __syncthreads();
  }
  if (threadIdx.x == 0) flag[0] = (cnt[0] >= 160) ? 1 : 0;
}

// ---------------- pack all small params into pb (bf16) ---------------------
// layout: [0,3840) qkvbias (bq|0|bv) | 3840 bo | 5120 g1 | 6400 be1 |
//         7680 g2 | 8960 be2 | 10240 b1(5120) | 15360 b2 | total 16640
__global__ __launch_bounds__(256) void pack_params_kernel(
    const void* bq, const void* bv, const void* bo, const void* g1,
    const void* be1, const void* g2, const void* be2, const void* b1,
    const void* b2, __bf16* __restrict__ pb, const int* __restrict__ flag) {
  const int isbf = flag[0];
  const int i = blockIdx.x * 256 + threadIdx.x;
  if (i >= 16640) return;
  auto ld = [&](const void* p, int j) -> float {
    return isbf ? (float)((const __bf16*)p)[j] : ((const float*)p)[j];
  };
  float v;
  if (i < 3840) {
    if (i < 1280) v = ld(bq, i);
    else if (i < 2560) v = 0.f;
    else v = ld(bv, i - 2560);
  } else if (i < 5120) v = ld(bo, i - 3840);
  else if (i < 6400) v = ld(g1, i - 5120);
  else if (i < 7680) v = ld(be1, i - 6400);
  else if (i < 8960) v = ld(g2, i - 7680);
  else if (i < 10240) v = ld(be2, i - 8960);
  else if (i < 15360) v = ld(b1, i - 10240);
  else v = ld(b2, i - 15360);
  pb[i] = (__bf16)v;
}

// ---------------- weight transpose: in (K,N) -> out (N,K), bf16 out --------
__device__ __forceinline__ void transpose_body(const void* in, __bf16* out,
                                               int K, int N, int isbf) {
  __shared__ __bf16 t[32][33];
  const int tx = threadIdx.x, ty = threadIdx.y;
  const int n0 = blockIdx.x * 32, k0 = blockIdx.y * 32;
  if (isbf) {
    const __bf16* s = (const __bf16*)in;
#pragma unroll
    for (int i = ty; i < 32; i += 8)
      t[i][tx] = s[(size_t)(k0 + i) * N + n0 + tx];
  } else {
    const float* s = (const float*)in;
#pragma unroll
    for (int i = ty; i < 32; i += 8)
      t[i][tx] = (__bf16)s[(size_t)(k0 + i) * N + n0 + tx];
  }
  __syncthreads();
#pragma unroll
  for (int i = ty; i < 32; i += 8)
    out[(size_t)(n0 + i) * K + k0 + tx] = t[tx][i];
}

__global__ __launch_bounds__(256) void transpose_kernel(const void* __restrict__ in,
                                                        __bf16* __restrict__ out,
                                                        int K, int N,
                                                        const int* __restrict__ flag) {
  transpose_body(in, out, K, N, flag[0]);
}

// fused Wq/Wk/Wv transpose -> contiguous Wqkvt[3840][1280]
__global__ __launch_bounds__(256) void transpose3_kernel(const void* __restrict__ Wq,
                                                         const void* __restrict__ Wk,
                                                         const void* __restrict__ Wv,
                                                         __bf16* __restrict__ out,
                                                         const int* __restrict__ flag) {
  const void* in = blockIdx.z == 0 ? Wq : (blockIdx.z == 1 ? Wk : Wv);
  transpose_body(in, out + (size_t)blockIdx.z * CDIM * CDIM, CDIM, CDIM, flag[0]);
}

// ---------------- activation transpose: [SEQ][.] -> [N][VTLD] --------------
__global__ __launch_bounds__(256) void transpose_act_kernel(const __bf16* __restrict__ in,
                                                            __bf16* __restrict__ out,
                                                            int istride) {
  __shared__ __bf16 t[32][33];
  const int tx = threadIdx.x, ty = threadIdx.y;
  const int n0 = blockIdx.x * 32, k0 = blockIdx.y * 32;
#pragma unroll
  for (int i = ty; i < 32; i += 8) {
    const int k = k0 + i;
    t[i][tx] = (k < SEQ) ? in[(size_t)k * istride + n0 + tx] : (__bf16)0.f;
  }
  __syncthreads();
#pragma unroll
  for (int i = ty; i < 32; i += 8) {
    const int kk = k0 + tx;
    if (kk < VTLD) out[(size_t)(n0 + i) * VTLD + kk] = t[tx][i];
  }
}

// ---------------- layernorm: 1 block per row; X dtype per flag if xflag ----
__global__ __launch_bounds__(256) void ln_kernel(const void* __restrict__ X,
                                                 const __bf16* __restrict__ gamma,
                                                 const __bf16* __restrict__ beta,
                                                 __bf16* __restrict__ Y,
                                                 int xflag, const int* __restrict__ flag) {
  const int isf32 = xflag ? (flag[0] == 0) : 0;
  const int row = blockIdx.x;
  float v[5];
  float s = 0.f, s2 = 0.f;
#pragma unroll
  for (int i = 0; i < 5; ++i) {
    const int c = threadIdx.x + 256 * i;
    const size_t idx = (size_t)row * CDIM + c;
    v[i] = isf32 ? ((const float*)X)[idx] : (float)((const __bf16*)X)[idx];
    s += v[i];
    s2 += v[i] * v[i];
  }
  const int lane = threadIdx.x & 63, wv = threadIdx.x >> 6;
#pragma unroll
  for (int off = 32; off > 0; off >>= 1) {
    s += __shfl_down(s, off);
    s2 += __shfl_down(s2, off);
  }
  __shared__ float red[8];
  if (lane == 0) { red[wv] = s; red[4 + wv] = s2; }
  __syncthreads();
  s = red[0] + red[1] + red[2] + red[3];
  s2 = red[4] + red[5] + red[6] + red[7];
  const float mu = s * (1.f / CDIM);
  const float var = s2 * (1.f / CDIM) - mu * mu;
  const float rstd = rsqrtf(fmaxf(var, 0.f) + 1e-5f);
#pragma unroll
  for (int i = 0; i < 5; ++i) {
    const int c = threadIdx.x + 256 * i;
    Y[(size_t)row * CDIM + c] =
        (__bf16)((v[i] - mu) * rstd * (float)gamma[c] + (float)beta[c]);
  }
}

// ---------------- GEMM 64x128 tile, BK=64 (2 stride-32 chunks) -------------
// grid (Mtiles, Ntiles, nsplit). nsplit>1: fp32 partials to Cv + z*M*N.
__global__ __launch_bounds__(256) void gemm64_kernel(
    const __bf16* __restrict__ A, const __bf16* __restrict__ Bt,
    const __bf16* __restrict__ bias, void* __restrict__ Cv,
    int M, int N, int K, int KS, int gelu, int nsplit) {
  __shared__ __bf16 As[2][64 * 32];
  __shared__ __bf16 Bs[2][128 * 32];
  const int bm = blockIdx.x, bn = blockIdx.y, sz = blockIdx.z;
  const int tid = threadIdx.x;
  const int lane = tid & 63, wave = tid >> 6;
  const int l16 = lane & 15, kq = (lane >> 4) << 3;
  const int lrow = lane >> 2, lcol = (lane & 3) << 3;
  const int wn = wave * 32;

  f32x4 acc[4][2];
  const f32x4 zero = {0.f, 0.f, 0.f, 0.f};
#pragma unroll
  for (int i = 0; i < 4; ++i)
#pragma unroll
    for (int j = 0; j < 2; ++j) acc[i][j] = zero;

  const int kbeg = sz * KS;
  int kend = kbeg + KS;
  if (kend > K) kend = K;

  int ga = bm * 64 + wave * 16 + lrow;
  if (ga > M - 1) ga = M - 1;  // clamp: garbage rows never stored
  const __bf16* Ap = A + (size_t)ga * K + lcol;

  for (int k0 = kbeg; k0 < kend; k0 += 64) {
#pragma unroll
    for (int c = 0; c < 2; ++c)
      GLOAD_LDS16(Ap + k0 + c * 32, &As[c][wave * 512]);
#pragma unroll
    for (int c = 0; c < 2; ++c)
#pragma unroll
      for (int t = 0; t < 2; ++t) {
        const int seg = t * 4 + wave;
        const int gb = bn * 128 + seg * 16 + lrow;  // N multiple of 128
        GLOAD_LDS16(Bt + (size_t)gb * K + k0 + c * 32 + lcol, &Bs[c][seg * 512]);
      }
    __syncthreads();
    bf16x8 af[4][2], bfr[2][2];
#pragma unroll
    for (int i = 0; i < 4; ++i)
#pragma unroll
      for (int c = 0; c < 2; ++c)
        af[i][c] = *(const bf16x8*)(&As[c][(i * 16 + l16) * 32 + kq]);
#pragma unroll
    for (int j = 0; j < 2; ++j)
#pragma unroll
      for (int c = 0; c < 2; ++c)
        bfr[j][c] = *(const bf16x8*)(&Bs[c][(wn + j * 16 + l16) * 32 + kq]);
#pragma unroll
    for (int i = 0; i < 4; ++i)
#pragma unroll
      for (int j = 0; j < 2; ++j)
#pragma unroll
        for (int c = 0; c < 2; ++c)
          acc[i][j] = __builtin_amdgcn_mfma_f32_16x16x32_bf16(af[i][c], bfr[j][c],
                                                              acc[i][j], 0, 0, 0);
    __syncthreads();
  }

  // epilogue: D[row][col], col = lane&15, row = (lane>>4)*4 + r
  const int rq4 = (lane >> 4) * 4;
  if (nsplit > 1) {
    float* P = (float*)Cv + (size_t)sz * M * N;
#pragma unroll
    for (int i = 0; i < 4; ++i)
#pragma unroll
      for (int r = 0; r < 4; ++r) {
        const int grow = bm * 64 + i * 16 + rq4 + r;
        if (grow >= M) continue;
#pragma unroll
        for (int j = 0; j < 2; ++j) {
          const int gcol = bn * 128 + wn + j * 16 + l16;
          P[(size_t)grow * N + gcol] = acc[i][j][r];
        }
      }
  } else {
    __bf16* Cb = (__bf16*)Cv;
#pragma unroll
    for (int i = 0; i < 4; ++i)
#pragma unroll
      for (int r = 0; r < 4; ++r) {
        const int grow = bm * 64 + i * 16 + rq4 + r;
        if (grow >= M) continue;
#pragma unroll
        for (int j = 0; j < 2; ++j) {
          const int gcol = bn * 128 + wn + j * 16 + l16;
          float vv = acc[i][j][r];
          if (bias) vv += (float)bias[gcol];
          if (gelu) vv = 0.5f * vv * (1.f + erff(vv * 0.70710678118654752f));
          Cb[(size_t)grow * N + gcol] = (__bf16)vv;
        }
      }
  }
}

// ---------------- split-K reduce: out = resid + sum(P) + bias --------------
__global__ __launch_bounds__(256) void reduce_kernel(
    const float* __restrict__ P, const __bf16* __restrict__ bias,
    const void* __restrict__ resid, void* __restrict__ out,
    int MN, int N, int S, int residflagged, int outflagged,
    const int* __restrict__ flag) {
  const int i = blockIdx.x * 256 + threadIdx.x;
  if (i >= MN) return;
  float v = 0.f;
  for (int s = 0; s < S; ++s) v += P[(size_t)s * MN + i];
  v += (float)bias[i % N];
  if (resid) {
    const int rf32 = residflagged ? (flag[0] == 0) : 0;
    v += rf32 ? ((const float*)resid)[i] : (float)((const __bf16*)resid)[i];
  }
  const int outbf = outflagged ? flag[0] : 1;
  if (outbf) ((__bf16*)out)[i] = (__bf16)v;
  else       ((float*)out)[i] = v;
}

// ---------------- MFMA flash attention, split-KV ---------------------------
// grid (24 q-tiles, 20 heads, 2 kv-halves). Each block: 64 queries x 12
// kv-tiles of 64 keys. Outputs UNNORMALIZED O-partials (fp32) + (m,l)/row.
__global__ __launch_bounds__(256) void attn_mfma_kernel(
    const __bf16* __restrict__ Q,    // fused base (+0), row stride rs
    const __bf16* __restrict__ Kk,   // fused base + 1280, row stride rs
    const __bf16* __restrict__ Vt,   // [CDIM][VTLD]
    float* __restrict__ Opart,       // [2][SEQ][CDIM]
    float* __restrict__ ml,          // [2][NHEAD][SEQ][2]
    int rs) {
  const int h = blockIdx.y;
  const int q0 = blockIdx.x * 64;
  const int z = blockIdx.z;
  const int tid = threadIdx.x;
  const int wave = tid >> 6, lane = tid & 63;
  const int l16 = lane & 15, quad = lane >> 4;

  __shared__ __bf16 Ks[64 * APAD];
  __shared__ __bf16 Vs[64 * APAD];
  __shared__ __bf16 Ps[4][16 * APAD];

  bf16x8 qf[2];
  {
    int q = q0 + wave * 16 + l16;
    if (q > SEQ - 1) q = SEQ - 1;
    const __bf16* qp = Q + (size_t)q * rs + h * DHEAD + quad * 8;
    qf[0] = *(const bf16x8*)(qp);
    qf[1] = *(const bf16x8*)(qp + 32);
  }

  f32x4 oacc[4];
  const f32x4 zero = {0.f, 0.f, 0.f, 0.f};
#pragma unroll
  for (int jt = 0; jt < 4; ++jt) oacc[jt] = zero;
  float mrow[4], lrow[4];
#pragma unroll
  for (int r = 0; r < 4; ++r) { mrow[r] = -30000.f; lrow[r] = 0.f; }

  const int srow = tid >> 2;
  const int scol = (tid & 3) << 4;

  const __bf16* Kbase = Kk + h * DHEAD;
  const __bf16* Vbase = Vt + (size_t)(h * DHEAD + srow) * VTLD;

  for (int kt = z * 12; kt < z * 12 + 12; ++kt) {
    const int key0 = kt * 64;
    __syncthreads();  // prior tile's Ks/Vs reads complete
    {
      int gk = key0 + srow;
      if (gk > SEQ - 1) gk = SEQ - 1;
      const __bf16* kp = Kbase + (size_t)gk * rs + scol;
      *(bf16x8*)(&Ks[srow * APAD + scol]) = *(const bf16x8*)(kp);
      *(bf16x8*)(&Ks[srow * APAD + scol + 8]) = *(const bf16x8*)(kp + 8);
      const __bf16* vp = Vbase + key0 + scol;
      *(bf16x8*)(&Vs[srow * APAD + scol]) = *(const bf16x8*)(vp);
      *(bf16x8*)(&Vs[srow * APAD + scol + 8]) = *(const bf16x8*)(vp + 8);
    }
    __syncthreads();

    // --- S = Q K^T (C-layout: row=q=quad*4+r, col=key=jt*16+l16) ---
    f32x4 s[4];
#pragma unroll
    for (int jt = 0; jt < 4; ++jt) s[jt] = zero;
#pragma unroll
    for (int jt = 0; jt < 4; ++jt)
#pragma unroll
      for (int ks = 0; ks < 2; ++ks) {
        const bf16x8 kf = *(const bf16x8*)(&Ks[(jt * 16 + l16) * APAD + ks * 32 + quad * 8]);
        s[jt] = __builtin_amdgcn_mfma_f32_16x16x32_bf16(qf[ks], kf, s[jt], 0, 0, 0);
      }

#pragma unroll
    for (int jt = 0; jt < 4; ++jt) {
      const int key = key0 + jt * 16 + l16;
#pragma unroll
      for (int r = 0; r < 4; ++r) {
        float sv = s[jt][r] * 0.125f;
        if (key >= SEQ) sv = -30000.f;
        s[jt][r] = sv;
      }
    }

    // online softmax update (P write is per-wave: no barrier needed after)
#pragma unroll
    for (int r = 0; r < 4; ++r) {
      float tmax = fmaxf(fmaxf(s[0][r], s[1][r]), fmaxf(s[2][r], s[3][r]));
#pragma unroll
      for (int off = 8; off > 0; off >>= 1) tmax = fmaxf(tmax, __shfl_xor(tmax, off));
      const float mnew = fmaxf(mrow[r], tmax);
      const float alpha = __expf(mrow[r] - mnew);
      mrow[r] = mnew;
      lrow[r] *= alpha;
#pragma unroll
      for (int jt = 0; jt < 4; ++jt) oacc[jt][r] *= alpha;
#pragma unroll
      for (int jt = 0; jt < 4; ++jt) {
        const float p = __expf(s[jt][r] - mnew);
        lrow[r] += p;
        Ps[wave][(quad * 4 + r) * APAD + jt * 16 + l16] = (__bf16)p;
      }
    }

    // --- O += P V (A=P via per-wave LDS round-trip, B=Vs) ---
    bf16x8 pf[2];
    pf[0] = *(const bf16x8*)(&Ps[wave][l16 * APAD + quad * 8]);
    pf[1] = *(const bf16x8*)(&Ps[wave][l16 * APAD + 32 + quad * 8]);
#pragma unroll
    for (int jt = 0; jt < 4; ++jt)
#pragma unroll
      for (int ks = 0; ks < 2; ++ks) {
        const bf16x8 vf = *(const bf16x8*)(&Vs[(jt * 16 + l16) * APAD + ks * 32 + quad * 8]);
        oacc[jt] = __builtin_amdgcn_mfma_f32_16x16x32_bf16(pf[ks], vf, oacc[jt], 0, 0, 0);
      }
  }

  // store unnormalized partials + (m, l)
  float* Oz = Opart + (size_t)z * SEQ * CDIM;
#pragma unroll
  for (int r = 0; r < 4; ++r) {
    float lt = lrow[r];
#pragma unroll
    for (int off = 8; off > 0; off >>= 1) lt += __shfl_xor(lt, off);
    const int q = q0 + wave * 16 + quad * 4 + r;
    if (q < SEQ) {
#pragma unroll
      for (int jt = 0; jt < 4; ++jt)
        Oz[(size_t)q * CDIM + h * DHEAD + jt * 16 + l16] = oacc[jt][r];
      if (l16 == 0) {
        const size_t mi = ((size_t)(z * NHEAD + h) * SEQ + q) * 2;
        ml[mi] = mrow[r];
        ml[mi + 1] = lt;
      }
    }
  }
}

// ---------------- combine the two kv-halves --------------------------------
__global__ __launch_bounds__(256) void attn_combine_kernel(
    const float* __restrict__ Op, const float* __restrict__ ml,
    __bf16* __restrict__ O) {
  const int i = blockIdx.x * 256 + threadIdx.x;
  if (i >= SEQ * CDIM) return;
  const int q = i / CDIM;
  const int h = (i % CDIM) >> 6;
  const size_t m1i = ((size_t)h * SEQ + q) * 2;
  const size_t m2i = ((size_t)(NHEAD + h) * SEQ + q) * 2;
  const float m1 = ml[m1i], l1 = ml[m1i + 1];
  const float m2 = ml[m2i], l2 = ml[m2i + 1];
  const float M = fmaxf(m1, m2);
  const float e1 = __expf(m1 - M), e2 = __expf(m2 - M);
  const float v = (e1 * Op[i] + e2 * Op[(size_t)SEQ * CDIM + i]) /
                  (e1 * l1 + e2 * l2);
  O[i] = (__bf16)v;
}

// ---------------- launch ----------------
extern "C" void kernel_launch(void* const* d_in, const int* in_sizes, int n_in,
                              void* d_out, int out_size, void* d_ws, size_t ws_size,
                              hipStream_t stream) {
  const void* x   = d_in[0];
  const void* Wq  = d_in[1];
  const void* bq  = d_in[2];
  const void* Wk  = d_in[3];
  const void* Wv  = d_in[4];
  const void* bv  = d_in[5];
  const void* Wo  = d_in[6];
  const void* bo  = d_in[7];
  const void* g1  = d_in[8];
  const void* be1 = d_in[9];
  const void* g2  = d_in[10];
  const void* be2 = d_in[11];
  const void* W1  = d_in[12];
  const void* bm1 = d_in[13];
  const void* W2  = d_in[14];
  const void* bm2 = d_in[15];

  char* ws = (char*)d_ws;
  size_t off = 0;
  auto alloc = [&](size_t elems) {
    __bf16* p = (__bf16*)(ws + off);
    off += elems * sizeof(__bf16);
    return p;
  };
  __bf16* Wqkvt = alloc((size_t)QKVN * CDIM);   // fused Wq^T|Wk^T|Wv^T
  __bf16* Wot   = alloc((size_t)CDIM * CDIM);
  __bf16* W1t   = alloc((size_t)CDIM * NMLP);
  __bf16* W2t   = alloc((size_t)CDIM * NMLP);
  __bf16* qkvb  = alloc((size_t)SEQ * QKVN);    // fused q|k|v; later x1|h2
  __bf16* hb    = alloc((size_t)SEQ * CDIM);    // ln1 out / attn out
  __bf16* mb    = alloc((size_t)SEQ * NMLP);    // mlp hidden; head = Vt
  __bf16* pb    = alloc(20480);                 // packed params
  off = (off + 15) & ~(size_t)15;
  float* pscr = (float*)(ws + off);             // O-partials / split-K partials
  off += (size_t)2 * SEQ * CDIM * sizeof(float);
  float* mlb = (float*)(ws + off);              // attn (m,l): 2 x 20 x 1500 x 2
  off += (size_t)2 * NHEAD * SEQ * 2 * sizeof(float);
  int* flag = (int*)(ws + off);

  __bf16* vtb  = mb;                 // Vt[CDIM][VTLD] (dead before MLP1)
  __bf16* x1b  = qkvb;               // x1 (qkv dead after attention)
  __bf16* h2b  = qkvb + (size_t)SEQ * CDIM;  // ln2 out

  __bf16* qkvbias = pb + 0;
  __bf16* bo_b  = pb + 3840;
  __bf16* g1_b  = pb + 5120;
  __bf16* be1_b = pb + 6400;
  __bf16* g2_b  = pb + 7680;
  __bf16* be2_b = pb + 8960;
  __bf16* b1_b  = pb + 10240;
  __bf16* b2_b  = pb + 15360;

  detect_kernel<<<1, 256, 0, stream>>>((const unsigned int*)x, flag);
  pack_params_kernel<<<65, 256, 0, stream>>>(bq, bv, bo, g1, be1, g2, be2,
                                             bm1, bm2, pb, flag);

  const dim3 tb(32, 8);
  transpose3_kernel<<<dim3(40, 40, 3), tb, 0, stream>>>(Wq, Wk, Wv, Wqkvt, flag);
  transpose_kernel<<<dim3(40, 40), tb, 0, stream>>>(Wo, Wot, CDIM, CDIM, flag);
  transpose_kernel<<<dim3(160, 40), tb, 0, stream>>>(W1, W1t, CDIM, NMLP, flag);
  transpose_kernel<<<dim3(40, 160), tb, 0, stream>>>(W2, W2t, NMLP, CDIM, flag);

  // h = LN1(x)  (x dtype per flag)
  ln_kernel<<<SEQ, 256, 0, stream>>>(x, g1_b, be1_b, hb, 1, flag);
  // qkv = h @ Wqkv^T + (bq|0|bv)   [1500][3840]
  gemm64_kernel<<<dim3(24, 30, 1), 256, 0, stream>>>(
      hb, Wqkvt, qkvbias, qkvb, SEQ, QKVN, CDIM, CDIM, 0, 1);
  // Vt = V^T (V = qkvb col-block 2)
  transpose_act_kernel<<<dim3(40, 47), tb, 0, stream>>>(qkvb + 2560, vtb, QKVN);
  // attention: split-KV partials, then combine -> hb
  attn_mfma_kernel<<<dim3(24, NHEAD, 2), 256, 0, stream>>>(
      qkvb, qkvb + 1280, vtb, pscr, mlb, QKVN);
  attn_combine_kernel<<<7500, 256, 0, stream>>>(pscr, mlb, hb);
  // attn @ Wo (split-K=2, fp32 partials)
  gemm64_kernel<<<dim3(24, 10, 2), 256, 0, stream>>>(
      hb, Wot, nullptr, pscr, SEQ, CDIM, CDIM, 640, 0, 2);
  // x1 = x + partials + bo   (x dtype per flag)
  reduce_kernel<<<7500, 256, 0, stream>>>(pscr, bo_b, x, x1b,
                                          SEQ * CDIM, CDIM, 2, 1, 0, flag);
  // h2 = LN2(x1)
  ln_kernel<<<SEQ, 256, 0, stream>>>(x1b, g2_b, be2_b, h2b, 0, flag);
  // m = gelu(h2 @ W1 + b1)
  gemm64_kernel<<<dim3(24, 40, 1), 256, 0, stream>>>(
      h2b, W1t, b1_b, mb, SEQ, NMLP, CDIM, CDIM, 1, 1);
  // m @ W2 (split-K=2)
  gemm64_kernel<<<dim3(24, 10, 2), 256, 0, stream>>>(
      mb, W2t, nullptr, pscr, SEQ, CDIM, NMLP, 2560, 0, 2);
  // out = x1 + partials + b2 (output dtype per flag)
  reduce_kernel<<<7500, 256, 0, stream>>>(pscr, b2_b, x1b, d_out,
                                          SEQ * CDIM, CDIM, 2, 0, 1, flag);
}